// Round 17
// baseline (355.680 us; speedup 1.0000x reference)
//
#include <hip/hip_runtime.h>
#include <math.h>

#define N_NODES 50000
#define N_EDGES 600000
#define DD 128
#define N_GRAPHS 8
#define N_TILES 9375  // 600000 / 64
#define EDGE_GRID 768 // 3 blocks/CU x 256 CUs (matches 48KB-LDS residency)

typedef __attribute__((ext_vector_type(4))) float f32x4;
typedef __attribute__((ext_vector_type(8))) __bf16 bf16x8;
typedef __attribute__((ext_vector_type(8))) unsigned short ushort8;
typedef __attribute__((ext_vector_type(4))) unsigned short ushort4v;

__device__ __forceinline__ unsigned short f2bf(float f) {
  unsigned u = __builtin_bit_cast(unsigned, f);
  return (unsigned short)((u + 0x7FFFu + ((u >> 16) & 1u)) >> 16);
}
__device__ __forceinline__ float bf2f(unsigned short h) {
  unsigned u = ((unsigned)h) << 16;
  return __builtin_bit_cast(float, u);
}

// 3-bit bijective swizzle for sW 16B chunks
__device__ __forceinline__ int swz_w(int row) {
  return ((row & 3) << 1) | ((row >> 2) & 1);
}

// ---------------- fused: weight conversion + degree count ----------------
__global__ void conv_and_count(const float* __restrict__ Wl, const float* __restrict__ Wr,
                               const float* __restrict__ We, unsigned short* __restrict__ wbf,
                               const int* __restrict__ ei, int* __restrict__ counts) {
  int i = blockIdx.x * 256 + threadIdx.x;
  if (i < 16384)       wbf[i] = f2bf(Wl[i]);
  else if (i < 32768)  wbf[i] = f2bf(Wr[i - 16384]);
  else if (i < 49152)  wbf[i] = f2bf(We[i - 32768]);
  if (i < N_EDGES) atomicAdd(&counts[ei[N_EDGES + i]], 1);
}

// ---------------- node transform: xlbf = bf16(x@Wl.T + bl), xrbf = bf16(x@Wr.T + br) ----------------
__global__ __launch_bounds__(256) void node_transform(
    const float* __restrict__ x, const unsigned short* __restrict__ Wlbf,
    const unsigned short* __restrict__ Wrbf, const float* __restrict__ bl,
    const float* __restrict__ br, unsigned short* __restrict__ xlbf,
    unsigned short* __restrict__ xrbf) {
  __shared__ unsigned short sX[64 * 128];
  int tid = threadIdx.x;
  int nb = blockIdx.x * 64;
#pragma unroll
  for (int rep = 0; rep < 4; ++rep) {
    int chunk = rep * 256 + tid;  // 0..1023
    int row = chunk >> 4;
    int c = chunk & 15;
    int n = nb + row;
    ushort8 v;
    if (n < N_NODES) {
      const float* s = x + (size_t)n * DD + c * 8;
      f32x4 a = *(const f32x4*)s;
      f32x4 b = *(const f32x4*)(s + 4);
      v[0]=f2bf(a[0]); v[1]=f2bf(a[1]); v[2]=f2bf(a[2]); v[3]=f2bf(a[3]);
      v[4]=f2bf(b[0]); v[5]=f2bf(b[1]); v[6]=f2bf(b[2]); v[7]=f2bf(b[3]);
    } else {
      v = (ushort8)0;
    }
    int sc = c ^ (row & 7);
    *(ushort8*)((char*)sX + row * 256 + sc * 16) = v;
  }
  __syncthreads();

  int lane = tid & 63, wave = tid >> 6;
  int er = lane & 15, g = lane >> 4;
  f32x4 z = {0.f, 0.f, 0.f, 0.f};
  f32x4 accL[8], accR[8];
#pragma unroll
  for (int i = 0; i < 8; ++i) { accL[i] = z; accR[i] = z; }

  bf16x8 bfrag[4];
  int row = wave * 16 + er;
#pragma unroll
  for (int k0 = 0; k0 < 4; ++k0) {
    int c = (k0 * 4 + g) ^ (row & 7);
    bfrag[k0] = *(const bf16x8*)((char*)sX + row * 256 + c * 16);
  }
#pragma unroll
  for (int ot = 0; ot < 8; ++ot) {
#pragma unroll
    for (int k0 = 0; k0 < 4; ++k0) {
      int aoff = (ot * 16 + er) * DD + k0 * 32 + g * 8;
      bf16x8 aL = *(const bf16x8*)(Wlbf + aoff);
      accL[ot] = __builtin_amdgcn_mfma_f32_16x16x32_bf16(aL, bfrag[k0], accL[ot], 0, 0, 0);
      bf16x8 aR = *(const bf16x8*)(Wrbf + aoff);
      accR[ot] = __builtin_amdgcn_mfma_f32_16x16x32_bf16(aR, bfrag[k0], accR[ot], 0, 0, 0);
    }
  }
  int n = nb + wave * 16 + er;
  if (n < N_NODES) {
#pragma unroll
    for (int ot = 0; ot < 8; ++ot) {
      int outc = ot * 16 + g * 4;
      f32x4 b4l = *(const f32x4*)(bl + outc);
      f32x4 b4r = *(const f32x4*)(br + outc);
      f32x4 vl = accL[ot] + b4l;
      f32x4 vr = accR[ot] + b4r;
      ushort4v sl, sr;
#pragma unroll
      for (int i = 0; i < 4; ++i) { sl[i] = f2bf(vl[i]); sr[i] = f2bf(vr[i]); }
      *(ushort4v*)(xlbf + (size_t)n * DD + outc) = sl;
      *(ushort4v*)(xrbf + (size_t)n * DD + outc) = sr;
    }
  }
}

// ---------------- edge kernel v10: persistent blocks, sW staged once, v6 phase order per tile ----------------
__global__ __launch_bounds__(256) void edge_kernel(
    const float* __restrict__ edge_attr, const int* __restrict__ ei,
    const unsigned short* __restrict__ Webf, const unsigned short* __restrict__ xlbf,
    const unsigned short* __restrict__ xrbf, const float* __restrict__ att,
    float* __restrict__ out_edge, int* __restrict__ cursor, int2* __restrict__ pairs) {
  __shared__ unsigned short sW[128 * 128];  // 32KB bf16 We, staged ONCE per block
  __shared__ unsigned short sS[64 * 128];   // 16KB bf16 xl[src]+xr[dst] per tile
  int tid = threadIdx.x;
  int lane = tid & 63, wave = tid >> 6;
  int er = lane & 15, g = lane >> 4;
  int lrow = wave * 16 + er;  // local edge row 0..63

  // ---- stage We -> sW once (L2-resident, coalesced, swizzled) ----
  {
    const ushort8* gw = (const ushort8*)Webf;  // 2048 16B chunks
#pragma unroll
    for (int k = 0; k < 8; ++k) {
      int cg = tid + 256 * k;
      int row = cg >> 4, c = cg & 15;
      ushort8 v = gw[cg];
      *(ushort8*)&sW[row * 128 + ((c ^ swz_w(row)) << 3)] = v;
    }
  }
  // sW visible after the first per-tile barrier below (before any sW read)

  for (int tile = blockIdx.x; tile < N_TILES; tile += EDGE_GRID) {
    size_t eb = (size_t)tile * 64;
    size_t e = eb + lrow;

    // ---- (1) issue this tile's HBM stream loads FIRST; consumed BEFORE the barrier ----
    const float* erow = edge_attr + e * DD;
    f32x4 ea0[4], ea1[4];
#pragma unroll
    for (int k0 = 0; k0 < 4; ++k0) {
      int off = k0 * 32 + g * 8;
      ea0[k0] = *(const f32x4*)(erow + off);
      ea1[k0] = *(const f32x4*)(erow + off + 4);
    }

    // ---- (2) stage bf16(xl[src]+xr[dst]) -> sS: half-wave per row, coalesced ----
    {
      int j0 = tid >> 5, l = tid & 31;  // 8 edges per iteration; l = 8B chunk 0..31
#pragma unroll
      for (int i = 0; i < 8; ++i) {
        int j = i * 8 + j0;
        int sn = ei[eb + j];
        int dn = ei[N_EDGES + eb + j];
        ushort4v a = *(const ushort4v*)(xlbf + (size_t)sn * DD + l * 4);
        ushort4v b = *(const ushort4v*)(xrbf + (size_t)dn * DD + l * 4);
        ushort4v s;
#pragma unroll
        for (int q = 0; q < 4; ++q) s[q] = f2bf(bf2f(a[q]) + bf2f(b[q]));
        *(ushort4v*)&sS[j * 128 + ((l ^ (j & 15)) << 2)] = s;
      }
    }

    // ---- (3) passthrough store + bf16 convert (stream loads have landed) ----
    float* orow = out_edge + e * DD;
    bf16x8 bfrag[4];
#pragma unroll
    for (int k0 = 0; k0 < 4; ++k0) {
      int off = k0 * 32 + g * 8;
      f32x4 a = ea0[k0], b = ea1[k0];
      *(f32x4*)(orow + off) = a;
      *(f32x4*)(orow + off + 4) = b;
      ushort8 v;
      v[0]=f2bf(a[0]); v[1]=f2bf(a[1]); v[2]=f2bf(a[2]); v[3]=f2bf(a[3]);
      v[4]=f2bf(b[0]); v[5]=f2bf(b[1]); v[6]=f2bf(b[2]); v[7]=f2bf(b[3]);
      bfrag[k0] = __builtin_bit_cast(bf16x8, v);
    }
    __syncthreads();  // sS (and on first iter sW) visible; all loads already consumed

    // ---- (4) MFMA: A-fragments from sW ----
    f32x4 z = {0.f, 0.f, 0.f, 0.f};
    f32x4 acc[8];
#pragma unroll
    for (int i = 0; i < 8; ++i) acc[i] = z;
#pragma unroll
    for (int ot = 0; ot < 8; ++ot) {
#pragma unroll
      for (int k0 = 0; k0 < 4; ++k0) {
        int row = ot * 16 + er;
        bf16x8 af = *(const bf16x8*)&sW[row * 128 + (((k0 * 4 + g) ^ swz_w(row)) << 3)];
        acc[ot] = __builtin_amdgcn_mfma_f32_16x16x32_bf16(af, bfrag[k0], acc[ot], 0, 0, 0);
      }
    }

    // ---- (5) epilogue: alpha = sum_d leaky(sum_lds + e_proj) * att[d] ----
    float part = 0.f;
#pragma unroll
    for (int ot = 0; ot < 8; ++ot) {
      int cl = (ot * 4 + g) ^ (lrow & 15);
      ushort4v s4 = *(const ushort4v*)&sS[lrow * 128 + (cl << 2)];
      f32x4 at4 = *(const f32x4*)(att + ot * 16 + g * 4);
#pragma unroll
      for (int i = 0; i < 4; ++i) {
        float m = bf2f(s4[i]) + acc[ot][i];
        m = m > 0.f ? m : 0.2f * m;
        part += m * at4[i];
      }
    }
    part += __shfl_xor(part, 16);
    part += __shfl_xor(part, 32);
    if (g == 0) {
      int dst_n = ei[N_EDGES + e];
      int src_n = ei[e];
      int pos = atomicAdd(&cursor[dst_n], 1);
      int2 pr;
      pr.x = src_n;
      pr.y = __builtin_bit_cast(int, part);
      pairs[pos] = pr;  // single 8B scatter
    }
    __syncthreads();  // protect sS before next tile's staging
  }
}

// ---------------- scan_a: per-block totals (+ zero stats once, block 0) ----------------
__global__ void scan_a(const int* __restrict__ counts, int* __restrict__ bsums,
                       float* __restrict__ stats) {
  __shared__ int s[256];
  int t = threadIdx.x;
  if (blockIdx.x == 0 && t < 24) stats[t] = 0.f;  // consumed only by stats_reduce1, later
  int i = blockIdx.x * 256 + t;
  s[t] = (i < N_NODES) ? counts[i] : 0;
  __syncthreads();
  for (int o = 128; o > 0; o >>= 1) {
    if (t < o) s[t] += s[t + o];
    __syncthreads();
  }
  if (t == 0) bsums[blockIdx.x] = s[0];
}

// ---------------- scan_c: block base from raw bsums + local scan ----------------
__global__ void scan_c(const int* __restrict__ counts, const int* __restrict__ bsums,
                       int* __restrict__ offsets, int* __restrict__ cursor) {
  __shared__ int sb[256];
  __shared__ int s[256];
  int t = threadIdx.x;
  int bv = (t < 196) ? bsums[t] : 0;
  sb[t] = bv;
  __syncthreads();
  for (int o = 1; o < 256; o <<= 1) {
    int add = (t >= o) ? sb[t - o] : 0;
    __syncthreads();
    sb[t] += add;
    __syncthreads();
  }
  int base = (blockIdx.x > 0) ? sb[blockIdx.x - 1] : 0;
  int i = blockIdx.x * 256 + t;
  int v = (i < N_NODES) ? counts[i] : 0;
  s[t] = v;
  __syncthreads();
  for (int o = 1; o < 256; o <<= 1) {
    int add = (t >= o) ? s[t - o] : 0;
    __syncthreads();
    s[t] += add;
    __syncthreads();
  }
  if (i < N_NODES) {
    int excl = s[t] - v + base;
    offsets[i] = excl;
    cursor[i] = excl;
  }
}

// ---------------- aggregate (r12 best-measured): softmax + weighted sum + stats partials ----------------
__global__ __launch_bounds__(256) void aggregate(
    const float* __restrict__ x, const int* __restrict__ counts,
    const int* __restrict__ offsets, const int2* __restrict__ pairs,
    const unsigned short* __restrict__ xlbf, const float* __restrict__ bias,
    const int* __restrict__ batch, float* __restrict__ yout,
    float* __restrict__ partials) {
  __shared__ float sbuf[24];
  int tid = threadIdx.x;
  int wave = tid >> 6;
  int lane = tid & 63;
  if (tid < 24) sbuf[tid] = 0.f;
  __syncthreads();
  int node = blockIdx.x * 4 + wave;  // 12500 * 4 == 50000 exactly
  int deg = counts[node];
  int off = offsets[node];
  float esum = 0.f;
  float a0=0.f, a1=0.f, b0=0.f, b1=0.f, c0=0.f, c1=0.f, e0=0.f, e1=0.f;
  for (int j0 = 0; j0 < deg; j0 += 64) {
    int nj = deg - j0; if (nj > 64) nj = 64;
    float ev = 0.f; int sv = 0;
    if (lane < nj) {
      int2 p = pairs[off + j0 + lane];
      sv = p.x;
      ev = __expf(__builtin_bit_cast(float, p.y));
    }
    esum += ev;
    int j = 0;
    for (; j + 4 <= nj; j += 4) {
      int s0 = __shfl(sv, j),     s1 = __shfl(sv, j + 1);
      int s2 = __shfl(sv, j + 2), s3 = __shfl(sv, j + 3);
      float w0 = __shfl(ev, j),     w1 = __shfl(ev, j + 1);
      float w2 = __shfl(ev, j + 2), w3 = __shfl(ev, j + 3);
      unsigned v0 = *(const unsigned*)(xlbf + (size_t)s0 * DD + lane * 2);
      unsigned v1 = *(const unsigned*)(xlbf + (size_t)s1 * DD + lane * 2);
      unsigned v2 = *(const unsigned*)(xlbf + (size_t)s2 * DD + lane * 2);
      unsigned v3 = *(const unsigned*)(xlbf + (size_t)s3 * DD + lane * 2);
      a0 += w0 * bf2f((unsigned short)(v0 & 0xffff)); a1 += w0 * bf2f((unsigned short)(v0 >> 16));
      b0 += w1 * bf2f((unsigned short)(v1 & 0xffff)); b1 += w1 * bf2f((unsigned short)(v1 >> 16));
      c0 += w2 * bf2f((unsigned short)(v2 & 0xffff)); c1 += w2 * bf2f((unsigned short)(v2 >> 16));
      e0 += w3 * bf2f((unsigned short)(v3 & 0xffff)); e1 += w3 * bf2f((unsigned short)(v3 >> 16));
    }
    for (; j < nj; ++j) {
      int s0 = __shfl(sv, j);
      float w0 = __shfl(ev, j);
      unsigned v0 = *(const unsigned*)(xlbf + (size_t)s0 * DD + lane * 2);
      a0 += w0 * bf2f((unsigned short)(v0 & 0xffff)); a1 += w0 * bf2f((unsigned short)(v0 >> 16));
    }
  }
#pragma unroll
  for (int o = 1; o < 64; o <<= 1) esum += __shfl_xor(esum, o);
  float inv = 1.f / (esum + 1e-16f);
  float r0 = ((a0 + b0) + (c0 + e0)) * inv;
  float r1 = ((a1 + b1) + (c1 + e1)) * inv;
  float2 xv = *(const float2*)(x + (size_t)node * DD + lane * 2);
  float2 b2 = *(const float2*)(bias + lane * 2);
  float y0 = xv.x + r0 + b2.x;
  float y1 = xv.y + r1 + b2.y;
  float2 yo = {y0, y1};
  *(float2*)(yout + (size_t)node * DD + lane * 2) = yo;
  float sy = y0 + y1;
  float syy = y0 * y0 + y1 * y1;
#pragma unroll
  for (int o = 1; o < 64; o <<= 1) {
    sy += __shfl_xor(sy, o);
    syy += __shfl_xor(syy, o);
  }
  if (lane == 0) {
    int gph = batch[node];
    atomicAdd(&sbuf[gph], sy);
    atomicAdd(&sbuf[8 + gph], syy);
    atomicAdd(&sbuf[16 + gph], 1.f);
  }
  __syncthreads();
  if (tid < 24) partials[blockIdx.x * 24 + tid] = sbuf[tid];
}

// ---------------- stats reduce (single stage): partials[12500][24] -> stats[24] via atomics ----------------
#define R1_BLOCKS 128
__global__ void stats_reduce1(const float* __restrict__ partials,
                              float* __restrict__ stats, int nblk) {
  __shared__ float sdata[192];
  int t = threadIdx.x;  // 192 threads
  int col = t % 24, seg = t / 24;  // seg 0..7
  int rows = (nblk + R1_BLOCKS - 1) / R1_BLOCKS;
  int r0 = blockIdx.x * rows;
  int r1 = r0 + rows; if (r1 > nblk) r1 = nblk;
  float s = 0.f;
  for (int b = r0 + seg; b < r1; b += 8) s += partials[b * 24 + col];
  sdata[t] = s;
  __syncthreads();
  if (t < 24) {
    float tot = 0.f;
#pragma unroll
    for (int k = 0; k < 8; ++k) tot += sdata[t + 24 * k];
    atomicAdd(&stats[t], tot);
  }
}

// ---------------- finalize: graph LayerNorm in-place on d_out ----------------
__global__ __launch_bounds__(256) void finalize(
    float* __restrict__ y, const int* __restrict__ batch, const float* __restrict__ lnw,
    const float* __restrict__ lnb, const float* __restrict__ stats) {
  int idx = blockIdx.x * 256 + threadIdx.x;  // float4 index
  size_t i = (size_t)idx * 4;
  int node = (int)(i >> 7);
  int c = (int)(i & 127);
  int gph = batch[node];
  float cnt = stats[16 + gph];
  float norm = fmaxf(cnt, 1.f) * 128.f;
  float mean = stats[gph] / norm;
  float var = stats[8 + gph] / norm - mean * mean;
  float rstd = rsqrtf(var + 1e-5f);
  f32x4 yv = *(f32x4*)(y + i);
  f32x4 w = *(const f32x4*)(lnw + c);
  f32x4 b = *(const f32x4*)(lnb + c);
  f32x4 r;
#pragma unroll
  for (int k = 0; k < 4; ++k) r[k] = (yv[k] - mean) * rstd * w[k] + b[k];
  *(f32x4*)(y + i) = r;
}

extern "C" void kernel_launch(void* const* d_in, const int* in_sizes, int n_in,
                              void* d_out, int out_size, void* d_ws, size_t ws_size,
                              hipStream_t stream) {
  (void)in_sizes; (void)n_in; (void)out_size; (void)ws_size;
  const float* x         = (const float*)d_in[0];
  const int* ei          = (const int*)d_in[1];
  const float* edge_attr = (const float*)d_in[2];
  // d_in[3] = memory (unused by reference output)
  const int* batch       = (const int*)d_in[4];
  const float* Wl        = (const float*)d_in[5];
  const float* bl        = (const float*)d_in[6];
  const float* Wr        = (const float*)d_in[7];
  const float* br        = (const float*)d_in[8];
  const float* We        = (const float*)d_in[9];
  const float* att       = (const float*)d_in[10];
  const float* bias      = (const float*)d_in[11];
  const float* lnw       = (const float*)d_in[12];
  const float* lnb       = (const float*)d_in[13];

  float* out_x = (float*)d_out;
  float* out_e = out_x + (size_t)N_NODES * DD;

  char* ws = (char*)d_ws;
  size_t o = 0;
  auto alloc = [&](size_t b) { size_t r = o; o += (b + 511) & ~(size_t)511; return r; };
  unsigned short* wbf = (unsigned short*)(ws + alloc(3 * 16384 * 2));
  float* stats        = (float*)(ws + alloc(32 * 4));
  int* counts         = (int*)(ws + alloc((size_t)N_NODES * 4));
  int* offsets        = (int*)(ws + alloc((size_t)N_NODES * 4));
  int* cursor         = (int*)(ws + alloc((size_t)N_NODES * 4));
  int* bsums          = (int*)(ws + alloc(256 * 4));
  int2* pairs         = (int2*)(ws + alloc((size_t)N_EDGES * 8));
  float* partials     = (float*)(ws + alloc((size_t)(N_NODES / 4) * 24 * 4));
  unsigned short* xlbf = (unsigned short*)(ws + alloc((size_t)N_NODES * DD * 2));
  unsigned short* xrbf = (unsigned short*)(ws + alloc((size_t)N_NODES * DD * 2));

  hipMemsetAsync(counts, 0, (size_t)N_NODES * 4, stream);

  conv_and_count<<<(N_EDGES + 255) / 256, 256, 0, stream>>>(Wl, Wr, We, wbf, ei, counts);
  node_transform<<<782, 256, 0, stream>>>(x, wbf, wbf + 16384, bl, br, xlbf, xrbf);
  scan_a<<<196, 256, 0, stream>>>(counts, bsums, stats);
  scan_c<<<196, 256, 0, stream>>>(counts, bsums, offsets, cursor);
  edge_kernel<<<EDGE_GRID, 256, 0, stream>>>(edge_attr, ei, wbf + 32768, xlbf, xrbf,
                                             att, out_e, cursor, pairs);
  aggregate<<<N_NODES / 4, 256, 0, stream>>>(x, counts, offsets, pairs, xlbf,
                                             bias, batch, out_x, partials);
  stats_reduce1<<<R1_BLOCKS, 192, 0, stream>>>(partials, stats, N_NODES / 4);
  finalize<<<(N_NODES * DD / 4) / 256, 256, 0, stream>>>(out_x, batch, lnw, lnb, stats);
}

// Round 18
// 309.720 us; speedup vs baseline: 1.1484x; 1.1484x over previous
//
#include <hip/hip_runtime.h>
#include <math.h>

#define N_NODES 50000
#define N_EDGES 600000
#define DD 128
#define N_GRAPHS 8

typedef __attribute__((ext_vector_type(4))) float f32x4;
typedef __attribute__((ext_vector_type(8))) __bf16 bf16x8;
typedef __attribute__((ext_vector_type(8))) unsigned short ushort8;
typedef __attribute__((ext_vector_type(4))) unsigned short ushort4v;

__device__ __forceinline__ unsigned short f2bf(float f) {
  unsigned u = __builtin_bit_cast(unsigned, f);
  return (unsigned short)((u + 0x7FFFu + ((u >> 16) & 1u)) >> 16);
}
__device__ __forceinline__ float bf2f(unsigned short h) {
  unsigned u = ((unsigned)h) << 16;
  return __builtin_bit_cast(float, u);
}

// 3-bit bijective swizzle for sW 16B chunks
__device__ __forceinline__ int swz_w(int row) {
  return ((row & 3) << 1) | ((row >> 2) & 1);
}

// ---------------- fused: weight conversion + degree count ----------------
__global__ void conv_and_count(const float* __restrict__ Wl, const float* __restrict__ Wr,
                               const float* __restrict__ We, unsigned short* __restrict__ wbf,
                               const int* __restrict__ ei, int* __restrict__ counts) {
  int i = blockIdx.x * 256 + threadIdx.x;
  if (i < 16384)       wbf[i] = f2bf(Wl[i]);
  else if (i < 32768)  wbf[i] = f2bf(Wr[i - 16384]);
  else if (i < 49152)  wbf[i] = f2bf(We[i - 32768]);
  if (i < N_EDGES) atomicAdd(&counts[ei[N_EDGES + i]], 1);
}

// ---------------- node transform: xlbf = bf16(x@Wl.T + bl), xrbf = bf16(x@Wr.T + br) ----------------
__global__ __launch_bounds__(256) void node_transform(
    const float* __restrict__ x, const unsigned short* __restrict__ Wlbf,
    const unsigned short* __restrict__ Wrbf, const float* __restrict__ bl,
    const float* __restrict__ br, unsigned short* __restrict__ xlbf,
    unsigned short* __restrict__ xrbf) {
  __shared__ unsigned short sX[64 * 128];
  int tid = threadIdx.x;
  int nb = blockIdx.x * 64;
#pragma unroll
  for (int rep = 0; rep < 4; ++rep) {
    int chunk = rep * 256 + tid;  // 0..1023
    int row = chunk >> 4;
    int c = chunk & 15;
    int n = nb + row;
    ushort8 v;
    if (n < N_NODES) {
      const float* s = x + (size_t)n * DD + c * 8;
      f32x4 a = *(const f32x4*)s;
      f32x4 b = *(const f32x4*)(s + 4);
      v[0]=f2bf(a[0]); v[1]=f2bf(a[1]); v[2]=f2bf(a[2]); v[3]=f2bf(a[3]);
      v[4]=f2bf(b[0]); v[5]=f2bf(b[1]); v[6]=f2bf(b[2]); v[7]=f2bf(b[3]);
    } else {
      v = (ushort8)0;
    }
    int sc = c ^ (row & 7);
    *(ushort8*)((char*)sX + row * 256 + sc * 16) = v;
  }
  __syncthreads();

  int lane = tid & 63, wave = tid >> 6;
  int er = lane & 15, g = lane >> 4;
  f32x4 z = {0.f, 0.f, 0.f, 0.f};
  f32x4 accL[8], accR[8];
#pragma unroll
  for (int i = 0; i < 8; ++i) { accL[i] = z; accR[i] = z; }

  bf16x8 bfrag[4];
  int row = wave * 16 + er;
#pragma unroll
  for (int k0 = 0; k0 < 4; ++k0) {
    int c = (k0 * 4 + g) ^ (row & 7);
    bfrag[k0] = *(const bf16x8*)((char*)sX + row * 256 + c * 16);
  }
#pragma unroll
  for (int ot = 0; ot < 8; ++ot) {
#pragma unroll
    for (int k0 = 0; k0 < 4; ++k0) {
      int aoff = (ot * 16 + er) * DD + k0 * 32 + g * 8;
      bf16x8 aL = *(const bf16x8*)(Wlbf + aoff);
      accL[ot] = __builtin_amdgcn_mfma_f32_16x16x32_bf16(aL, bfrag[k0], accL[ot], 0, 0, 0);
      bf16x8 aR = *(const bf16x8*)(Wrbf + aoff);
      accR[ot] = __builtin_amdgcn_mfma_f32_16x16x32_bf16(aR, bfrag[k0], accR[ot], 0, 0, 0);
    }
  }
  int n = nb + wave * 16 + er;
  if (n < N_NODES) {
#pragma unroll
    for (int ot = 0; ot < 8; ++ot) {
      int outc = ot * 16 + g * 4;
      f32x4 b4l = *(const f32x4*)(bl + outc);
      f32x4 b4r = *(const f32x4*)(br + outc);
      f32x4 vl = accL[ot] + b4l;
      f32x4 vr = accR[ot] + b4r;
      ushort4v sl, sr;
#pragma unroll
      for (int i = 0; i < 4; ++i) { sl[i] = f2bf(vl[i]); sr[i] = f2bf(vr[i]); }
      *(ushort4v*)(xlbf + (size_t)n * DD + outc) = sl;
      *(ushort4v*)(xrbf + (size_t)n * DD + outc) = sr;
    }
  }
}

// ---------------- edge kernel v6 (r12 proven): sW+sS 48KB, T14 early loads consumed pre-barrier ----------------
__global__ __launch_bounds__(256) void edge_kernel(
    const float* __restrict__ edge_attr, const int* __restrict__ ei,
    const unsigned short* __restrict__ Webf, const unsigned short* __restrict__ xlbf,
    const unsigned short* __restrict__ xrbf, const float* __restrict__ att,
    float* __restrict__ out_edge, int* __restrict__ cursor, int2* __restrict__ pairs) {
  __shared__ unsigned short sW[128 * 128];  // 32KB bf16 We, 16B-chunk swizzled
  __shared__ unsigned short sS[64 * 128];   // 16KB bf16 xl[src]+xr[dst], 8B-chunk swizzled
  int tid = threadIdx.x;
  size_t eb = (size_t)blockIdx.x * 64;  // 9375 * 64 == 600000 exactly

  int lane = tid & 63, wave = tid >> 6;
  int er = lane & 15, g = lane >> 4;
  int lrow = wave * 16 + er;  // local edge row 0..63
  size_t e = eb + lrow;

  // ---- (1) issue the HBM stream loads FIRST; latency hides under staging; consumed BEFORE barrier ----
  const float* erow = edge_attr + e * DD;
  f32x4 ea0[4], ea1[4];
#pragma unroll
  for (int k0 = 0; k0 < 4; ++k0) {
    int off = k0 * 32 + g * 8;
    ea0[k0] = *(const f32x4*)(erow + off);
    ea1[k0] = *(const f32x4*)(erow + off + 4);
  }

  // ---- (2) stage We -> sW (L2-resident, coalesced, swizzled) ----
  {
    const ushort8* gw = (const ushort8*)Webf;  // 2048 16B chunks
#pragma unroll
    for (int k = 0; k < 8; ++k) {
      int cg = tid + 256 * k;
      int row = cg >> 4, c = cg & 15;
      ushort8 v = gw[cg];
      *(ushort8*)&sW[row * 128 + ((c ^ swz_w(row)) << 3)] = v;
    }
  }

  // ---- (3) stage bf16(xl[src]+xr[dst]) -> sS: half-wave per row, full-line coalesced ----
  {
    int j0 = tid >> 5, l = tid & 31;  // 8 edges per iteration; l = 8B chunk 0..31
#pragma unroll
    for (int i = 0; i < 8; ++i) {
      int j = i * 8 + j0;
      int sn = ei[eb + j];
      int dn = ei[N_EDGES + eb + j];
      ushort4v a = *(const ushort4v*)(xlbf + (size_t)sn * DD + l * 4);
      ushort4v b = *(const ushort4v*)(xrbf + (size_t)dn * DD + l * 4);
      ushort4v s;
#pragma unroll
      for (int q = 0; q < 4; ++q) s[q] = f2bf(bf2f(a[q]) + bf2f(b[q]));
      *(ushort4v*)&sS[j * 128 + ((l ^ (j & 15)) << 2)] = s;
    }
  }

  // ---- (4) passthrough store + bf16 convert (stream loads have landed by now) ----
  float* orow = out_edge + e * DD;
  bf16x8 bfrag[4];
#pragma unroll
  for (int k0 = 0; k0 < 4; ++k0) {
    int off = k0 * 32 + g * 8;
    f32x4 a = ea0[k0], b = ea1[k0];
    *(f32x4*)(orow + off) = a;
    *(f32x4*)(orow + off + 4) = b;
    ushort8 v;
    v[0]=f2bf(a[0]); v[1]=f2bf(a[1]); v[2]=f2bf(a[2]); v[3]=f2bf(a[3]);
    v[4]=f2bf(b[0]); v[5]=f2bf(b[1]); v[6]=f2bf(b[2]); v[7]=f2bf(b[3]);
    bfrag[k0] = __builtin_bit_cast(bf16x8, v);
  }
  __syncthreads();

  // ---- (5) MFMA: A-fragments from sW ----
  f32x4 z = {0.f, 0.f, 0.f, 0.f};
  f32x4 acc[8];
#pragma unroll
  for (int i = 0; i < 8; ++i) acc[i] = z;
#pragma unroll
  for (int ot = 0; ot < 8; ++ot) {
#pragma unroll
    for (int k0 = 0; k0 < 4; ++k0) {
      int row = ot * 16 + er;
      bf16x8 af = *(const bf16x8*)&sW[row * 128 + (((k0 * 4 + g) ^ swz_w(row)) << 3)];
      acc[ot] = __builtin_amdgcn_mfma_f32_16x16x32_bf16(af, bfrag[k0], acc[ot], 0, 0, 0);
    }
  }

  // ---- (6) epilogue: alpha = sum_d leaky(sum_lds + e_proj) * att[d], d = ot*16+g*4+i ----
  float part = 0.f;
#pragma unroll
  for (int ot = 0; ot < 8; ++ot) {
    int cl = (ot * 4 + g) ^ (lrow & 15);
    ushort4v s4 = *(const ushort4v*)&sS[lrow * 128 + (cl << 2)];
    f32x4 at4 = *(const f32x4*)(att + ot * 16 + g * 4);
#pragma unroll
    for (int i = 0; i < 4; ++i) {
      float m = bf2f(s4[i]) + acc[ot][i];
      m = m > 0.f ? m : 0.2f * m;
      part += m * at4[i];
    }
  }
  part += __shfl_xor(part, 16);
  part += __shfl_xor(part, 32);
  if (g == 0) {
    int dst_n = ei[N_EDGES + e];
    int src_n = ei[e];
    int pos = atomicAdd(&cursor[dst_n], 1);
    int2 pr;
    pr.x = src_n;
    pr.y = __builtin_bit_cast(int, part);
    pairs[pos] = pr;  // single 8B scatter
  }
}

// ---------------- scan_a: per-block totals (+ zero stats once, block 0) ----------------
__global__ void scan_a(const int* __restrict__ counts, int* __restrict__ bsums,
                       float* __restrict__ stats) {
  __shared__ int s[256];
  int t = threadIdx.x;
  if (blockIdx.x == 0 && t < 24) stats[t] = 0.f;  // consumed only by stats_reduce1, later
  int i = blockIdx.x * 256 + t;
  s[t] = (i < N_NODES) ? counts[i] : 0;
  __syncthreads();
  for (int o = 128; o > 0; o >>= 1) {
    if (t < o) s[t] += s[t + o];
    __syncthreads();
  }
  if (t == 0) bsums[blockIdx.x] = s[0];
}

// ---------------- scan_c: block base from raw bsums + local scan (scan_b folded in) ----------------
__global__ void scan_c(const int* __restrict__ counts, const int* __restrict__ bsums,
                       int* __restrict__ offsets, int* __restrict__ cursor) {
  __shared__ int sb[256];
  __shared__ int s[256];
  int t = threadIdx.x;
  int bv = (t < 196) ? bsums[t] : 0;
  sb[t] = bv;
  __syncthreads();
  for (int o = 1; o < 256; o <<= 1) {
    int add = (t >= o) ? sb[t - o] : 0;
    __syncthreads();
    sb[t] += add;
    __syncthreads();
  }
  int base = (blockIdx.x > 0) ? sb[blockIdx.x - 1] : 0;
  int i = blockIdx.x * 256 + t;
  int v = (i < N_NODES) ? counts[i] : 0;
  s[t] = v;
  __syncthreads();
  for (int o = 1; o < 256; o <<= 1) {
    int add = (t >= o) ? s[t - o] : 0;
    __syncthreads();
    s[t] += add;
    __syncthreads();
  }
  if (i < N_NODES) {
    int excl = s[t] - v + base;
    offsets[i] = excl;
    cursor[i] = excl;
  }
}

// ---------------- aggregate (r12 best-measured): softmax + weighted sum + stats partials ----------------
__global__ __launch_bounds__(256) void aggregate(
    const float* __restrict__ x, const int* __restrict__ counts,
    const int* __restrict__ offsets, const int2* __restrict__ pairs,
    const unsigned short* __restrict__ xlbf, const float* __restrict__ bias,
    const int* __restrict__ batch, float* __restrict__ yout,
    float* __restrict__ partials) {
  __shared__ float sbuf[24];
  int tid = threadIdx.x;
  int wave = tid >> 6;
  int lane = tid & 63;
  if (tid < 24) sbuf[tid] = 0.f;
  __syncthreads();
  int node = blockIdx.x * 4 + wave;  // 12500 * 4 == 50000 exactly
  int deg = counts[node];
  int off = offsets[node];
  float esum = 0.f;
  float a0=0.f, a1=0.f, b0=0.f, b1=0.f, c0=0.f, c1=0.f, e0=0.f, e1=0.f;
  for (int j0 = 0; j0 < deg; j0 += 64) {
    int nj = deg - j0; if (nj > 64) nj = 64;
    float ev = 0.f; int sv = 0;
    if (lane < nj) {
      int2 p = pairs[off + j0 + lane];
      sv = p.x;
      ev = __expf(__builtin_bit_cast(float, p.y));
    }
    esum += ev;
    int j = 0;
    for (; j + 4 <= nj; j += 4) {
      int s0 = __shfl(sv, j),     s1 = __shfl(sv, j + 1);
      int s2 = __shfl(sv, j + 2), s3 = __shfl(sv, j + 3);
      float w0 = __shfl(ev, j),     w1 = __shfl(ev, j + 1);
      float w2 = __shfl(ev, j + 2), w3 = __shfl(ev, j + 3);
      unsigned v0 = *(const unsigned*)(xlbf + (size_t)s0 * DD + lane * 2);
      unsigned v1 = *(const unsigned*)(xlbf + (size_t)s1 * DD + lane * 2);
      unsigned v2 = *(const unsigned*)(xlbf + (size_t)s2 * DD + lane * 2);
      unsigned v3 = *(const unsigned*)(xlbf + (size_t)s3 * DD + lane * 2);
      a0 += w0 * bf2f((unsigned short)(v0 & 0xffff)); a1 += w0 * bf2f((unsigned short)(v0 >> 16));
      b0 += w1 * bf2f((unsigned short)(v1 & 0xffff)); b1 += w1 * bf2f((unsigned short)(v1 >> 16));
      c0 += w2 * bf2f((unsigned short)(v2 & 0xffff)); c1 += w2 * bf2f((unsigned short)(v2 >> 16));
      e0 += w3 * bf2f((unsigned short)(v3 & 0xffff)); e1 += w3 * bf2f((unsigned short)(v3 >> 16));
    }
    for (; j < nj; ++j) {
      int s0 = __shfl(sv, j);
      float w0 = __shfl(ev, j);
      unsigned v0 = *(const unsigned*)(xlbf + (size_t)s0 * DD + lane * 2);
      a0 += w0 * bf2f((unsigned short)(v0 & 0xffff)); a1 += w0 * bf2f((unsigned short)(v0 >> 16));
    }
  }
#pragma unroll
  for (int o = 1; o < 64; o <<= 1) esum += __shfl_xor(esum, o);
  float inv = 1.f / (esum + 1e-16f);
  float r0 = ((a0 + b0) + (c0 + e0)) * inv;
  float r1 = ((a1 + b1) + (c1 + e1)) * inv;
  float2 xv = *(const float2*)(x + (size_t)node * DD + lane * 2);
  float2 b2 = *(const float2*)(bias + lane * 2);
  float y0 = xv.x + r0 + b2.x;
  float y1 = xv.y + r1 + b2.y;
  float2 yo = {y0, y1};
  *(float2*)(yout + (size_t)node * DD + lane * 2) = yo;
  float sy = y0 + y1;
  float syy = y0 * y0 + y1 * y1;
#pragma unroll
  for (int o = 1; o < 64; o <<= 1) {
    sy += __shfl_xor(sy, o);
    syy += __shfl_xor(syy, o);
  }
  if (lane == 0) {
    int gph = batch[node];
    atomicAdd(&sbuf[gph], sy);
    atomicAdd(&sbuf[8 + gph], syy);
    atomicAdd(&sbuf[16 + gph], 1.f);
  }
  __syncthreads();
  if (tid < 24) partials[blockIdx.x * 24 + tid] = sbuf[tid];
}

// ---------------- stats reduce (single stage): partials[12500][24] -> stats[24] via atomics ----------------
#define R1_BLOCKS 128
__global__ void stats_reduce1(const float* __restrict__ partials,
                              float* __restrict__ stats, int nblk) {
  __shared__ float sdata[192];
  int t = threadIdx.x;  // 192 threads
  int col = t % 24, seg = t / 24;  // seg 0..7
  int rows = (nblk + R1_BLOCKS - 1) / R1_BLOCKS;
  int r0 = blockIdx.x * rows;
  int r1 = r0 + rows; if (r1 > nblk) r1 = nblk;
  float s = 0.f;
  for (int b = r0 + seg; b < r1; b += 8) s += partials[b * 24 + col];
  sdata[t] = s;
  __syncthreads();
  if (t < 24) {
    float tot = 0.f;
#pragma unroll
    for (int k = 0; k < 8; ++k) tot += sdata[t + 24 * k];
    atomicAdd(&stats[t], tot);
  }
}

// ---------------- finalize: graph LayerNorm in-place on d_out ----------------
__global__ __launch_bounds__(256) void finalize(
    float* __restrict__ y, const int* __restrict__ batch, const float* __restrict__ lnw,
    const float* __restrict__ lnb, const float* __restrict__ stats) {
  int idx = blockIdx.x * 256 + threadIdx.x;  // float4 index
  size_t i = (size_t)idx * 4;
  int node = (int)(i >> 7);
  int c = (int)(i & 127);
  int gph = batch[node];
  float cnt = stats[16 + gph];
  float norm = fmaxf(cnt, 1.f) * 128.f;
  float mean = stats[gph] / norm;
  float var = stats[8 + gph] / norm - mean * mean;
  float rstd = rsqrtf(var + 1e-5f);
  f32x4 yv = *(f32x4*)(y + i);
  f32x4 w = *(const f32x4*)(lnw + c);
  f32x4 b = *(const f32x4*)(lnb + c);
  f32x4 r;
#pragma unroll
  for (int k = 0; k < 4; ++k) r[k] = (yv[k] - mean) * rstd * w[k] + b[k];
  *(f32x4*)(y + i) = r;
}

extern "C" void kernel_launch(void* const* d_in, const int* in_sizes, int n_in,
                              void* d_out, int out_size, void* d_ws, size_t ws_size,
                              hipStream_t stream) {
  (void)in_sizes; (void)n_in; (void)out_size; (void)ws_size;
  const float* x         = (const float*)d_in[0];
  const int* ei          = (const int*)d_in[1];
  const float* edge_attr = (const float*)d_in[2];
  // d_in[3] = memory (unused by reference output)
  const int* batch       = (const int*)d_in[4];
  const float* Wl        = (const float*)d_in[5];
  const float* bl        = (const float*)d_in[6];
  const float* Wr        = (const float*)d_in[7];
  const float* br        = (const float*)d_in[8];
  const float* We        = (const float*)d_in[9];
  const float* att       = (const float*)d_in[10];
  const float* bias      = (const float*)d_in[11];
  const float* lnw       = (const float*)d_in[12];
  const float* lnb       = (const float*)d_in[13];

  float* out_x = (float*)d_out;
  float* out_e = out_x + (size_t)N_NODES * DD;

  char* ws = (char*)d_ws;
  size_t o = 0;
  auto alloc = [&](size_t b) { size_t r = o; o += (b + 511) & ~(size_t)511; return r; };
  unsigned short* wbf = (unsigned short*)(ws + alloc(3 * 16384 * 2));
  float* stats        = (float*)(ws + alloc(32 * 4));
  int* counts         = (int*)(ws + alloc((size_t)N_NODES * 4));
  int* offsets        = (int*)(ws + alloc((size_t)N_NODES * 4));
  int* cursor         = (int*)(ws + alloc((size_t)N_NODES * 4));
  int* bsums          = (int*)(ws + alloc(256 * 4));
  int2* pairs         = (int2*)(ws + alloc((size_t)N_EDGES * 8));
  float* partials     = (float*)(ws + alloc((size_t)(N_NODES / 4) * 24 * 4));
  unsigned short* xlbf = (unsigned short*)(ws + alloc((size_t)N_NODES * DD * 2));
  unsigned short* xrbf = (unsigned short*)(ws + alloc((size_t)N_NODES * DD * 2));

  hipMemsetAsync(counts, 0, (size_t)N_NODES * 4, stream);

  conv_and_count<<<(N_EDGES + 255) / 256, 256, 0, stream>>>(Wl, Wr, We, wbf, ei, counts);
  node_transform<<<782, 256, 0, stream>>>(x, wbf, wbf + 16384, bl, br, xlbf, xrbf);
  scan_a<<<196, 256, 0, stream>>>(counts, bsums, stats);
  scan_c<<<196, 256, 0, stream>>>(counts, bsums, offsets, cursor);
  edge_kernel<<<N_EDGES / 64, 256, 0, stream>>>(edge_attr, ei, wbf + 32768, xlbf, xrbf,
                                                att, out_e, cursor, pairs);
  aggregate<<<N_NODES / 4, 256, 0, stream>>>(x, counts, offsets, pairs, xlbf,
                                             bias, batch, out_x, partials);
  stats_reduce1<<<R1_BLOCKS, 192, 0, stream>>>(partials, stats, N_NODES / 4);
  finalize<<<(N_NODES * DD / 4) / 256, 256, 0, stream>>>(out_x, batch, lnw, lnb, stats);
}